// Round 1
// baseline (400.888 us; speedup 1.0000x reference)
//
#include <hip/hip_runtime.h>
#include <stdint.h>

#define Bb   4
#define Ss   1024
#define MEMm 1024
#define Tt   2048
#define Dd   1024
#define Hh   16
#define DKk  64

typedef unsigned short u16;
using f32x4 = __attribute__((ext_vector_type(4))) float;
using s16x8 = __attribute__((ext_vector_type(8))) short;

__device__ __forceinline__ u16 f2bf(float x) {
  union { float f; uint32_t u; } c; c.f = x;
  uint32_t u = c.u;
  return (u16)((u + 0x7FFFu + ((u >> 16) & 1u)) >> 16);
}

__device__ __forceinline__ f32x4 mfma16(s16x8 a, s16x8 b, f32x4 c) {
  return __builtin_amdgcn_mfma_f32_16x16x32_bf16(a, b, c, 0, 0, 0);
}

// ---------------------------------------------------------------------------
// NT GEMM: Y[n,m] = sum_k X[n,k] * W[m,k], K = 1024. Tile 64x64, 4 waves.
// Inline fp32 -> bf16 cast during LDS staging. Epilogue variants:
//  0: QU/QV  (add u / v_bias, write [B,H,S,DK] bf16 x2)
//  1: KH     ([B,H,T,DK] bf16)
//  2: VT     ([B,H,DK,T] bf16, transposed)
//  3: RH     ([H,T,DK] bf16)
//  4: OUT    ([N,1024] fp32)
// ---------------------------------------------------------------------------
template <int EPI>
__global__ __launch_bounds__(256)
void gemm_nt(const float* __restrict__ X, const float* __restrict__ W,
             void* __restrict__ O1ptr, void* __restrict__ O2ptr,
             const float* __restrict__ bias1, const float* __restrict__ bias2) {
  __shared__ u16 As[64][40];
  __shared__ u16 Bs[64][40];
  const int tid  = threadIdx.x;
  const int lane = tid & 63;
  const int wave = tid >> 6;
  const int fr = lane & 15, fq = lane >> 4;
  const int n0 = blockIdx.x * 64, m0 = blockIdx.y * 64;
  const int wr = (wave >> 1) * 32, wc = (wave & 1) * 32;
  const int srow = tid >> 2;
  const int scol = (tid & 3) * 8;

  f32x4 acc[2][2] = {};

  const float* xa = X + (size_t)(n0 + srow) * Dd + scol;
  const float* wa = W + (size_t)(m0 + srow) * Dd + scol;

  for (int k0 = 0; k0 < Dd; k0 += 32) {
    float4 a0 = *(const float4*)(xa + k0);
    float4 a1 = *(const float4*)(xa + k0 + 4);
    float4 b0 = *(const float4*)(wa + k0);
    float4 b1 = *(const float4*)(wa + k0 + 4);
    __syncthreads();  // protect previous iteration's reads
    uint4 pa, pb;
    pa.x = f2bf(a0.x) | ((unsigned)f2bf(a0.y) << 16);
    pa.y = f2bf(a0.z) | ((unsigned)f2bf(a0.w) << 16);
    pa.z = f2bf(a1.x) | ((unsigned)f2bf(a1.y) << 16);
    pa.w = f2bf(a1.z) | ((unsigned)f2bf(a1.w) << 16);
    pb.x = f2bf(b0.x) | ((unsigned)f2bf(b0.y) << 16);
    pb.y = f2bf(b0.z) | ((unsigned)f2bf(b0.w) << 16);
    pb.z = f2bf(b1.x) | ((unsigned)f2bf(b1.y) << 16);
    pb.w = f2bf(b1.z) | ((unsigned)f2bf(b1.w) << 16);
    *(uint4*)&As[srow][scol] = pa;
    *(uint4*)&Bs[srow][scol] = pb;
    __syncthreads();
    s16x8 af0 = *(const s16x8*)&As[wr + fr][fq * 8];
    s16x8 af1 = *(const s16x8*)&As[wr + 16 + fr][fq * 8];
    s16x8 bf0 = *(const s16x8*)&Bs[wc + fr][fq * 8];
    s16x8 bf1 = *(const s16x8*)&Bs[wc + 16 + fr][fq * 8];
    acc[0][0] = mfma16(af0, bf0, acc[0][0]);
    acc[0][1] = mfma16(af0, bf1, acc[0][1]);
    acc[1][0] = mfma16(af1, bf0, acc[1][0]);
    acc[1][1] = mfma16(af1, bf1, acc[1][1]);
  }

#pragma unroll
  for (int i = 0; i < 2; ++i)
#pragma unroll
    for (int j = 0; j < 2; ++j)
#pragma unroll
      for (int r = 0; r < 4; ++r) {
        int n = n0 + wr + i * 16 + fq * 4 + r;
        int m = m0 + wc + j * 16 + fr;
        float y = acc[i][j][r];
        if constexpr (EPI == 0) {
          int b = n >> 10, s = n & 1023, h = m >> 6, dk = m & 63;
          size_t idx = ((size_t)(b * Hh + h) * Ss + s) * DKk + dk;
          ((u16*)O1ptr)[idx] = f2bf(y + bias1[m]);
          ((u16*)O2ptr)[idx] = f2bf(y + bias2[m]);
        } else if constexpr (EPI == 1) {
          int b = n >> 11, t = n & 2047, h = m >> 6, dk = m & 63;
          ((u16*)O1ptr)[((size_t)(b * Hh + h) * Tt + t) * DKk + dk] = f2bf(y);
        } else if constexpr (EPI == 2) {
          int b = n >> 11, t = n & 2047, h = m >> 6, dk = m & 63;
          ((u16*)O1ptr)[((size_t)(b * Hh + h) * DKk + dk) * Tt + t] = f2bf(y);
        } else if constexpr (EPI == 3) {
          int h = m >> 6, dk = m & 63;
          ((u16*)O1ptr)[((size_t)h * Tt + n) * DKk + dk] = f2bf(y);
        } else {
          ((float*)O1ptr)[(size_t)n * Dd + m] = y;
        }
      }
}

// ---------------------------------------------------------------------------
// Fused TXL attention. Block = 64 q-rows of one (b,h); 4 waves x 16 rows.
// Iterates key chunks of 64; AC via MFMA vs K; BD via banded G-strip MFMA vs
// circulant-indexed Rh rows, gathered G[p, p+q] through LDS; online softmax;
// PV via MFMA vs pre-transposed V. Writes fp32 concat [B,S,D].
// ---------------------------------------------------------------------------
__global__ __launch_bounds__(256)
void attn_kernel(const u16* __restrict__ QU, const u16* __restrict__ QV,
                 const u16* __restrict__ KH, const u16* __restrict__ VT,
                 const u16* __restrict__ RH, float* __restrict__ CONCAT) {
  __shared__ u16 Ks[64][72];
  __shared__ u16 Vs[64][72];
  __shared__ u16 Re[128][72];
  __shared__ float Gl[4][16][80];
  __shared__ u16 Pl[4][16][72];

  const int tid = threadIdx.x;
  const int wave = tid >> 6, lane = tid & 63;
  const int fr = lane & 15, fq = lane >> 4;
  const int i0 = blockIdx.x * 64;
  const int h = blockIdx.y, b = blockIdx.z;
  const int r0 = i0 + wave * 16;

  const u16* quB = QU + (size_t)(b * Hh + h) * Ss * DKk;
  const u16* qvB = QV + (size_t)(b * Hh + h) * Ss * DKk;
  const u16* khB = KH + (size_t)(b * Hh + h) * Tt * DKk;
  const u16* vtB = VT + (size_t)(b * Hh + h) * DKk * Tt;
  const u16* rhB = RH + (size_t)h * Tt * DKk;

  s16x8 qu0 = *(const s16x8*)(quB + (size_t)(r0 + fr) * DKk + fq * 8);
  s16x8 qu1 = *(const s16x8*)(quB + (size_t)(r0 + fr) * DKk + 32 + fq * 8);
  s16x8 qv0 = *(const s16x8*)(qvB + (size_t)(r0 + fr) * DKk + fq * 8);
  s16x8 qv1 = *(const s16x8*)(qvB + (size_t)(r0 + fr) * DKk + 32 + fq * 8);

  f32x4 oacc[4] = {};
  float mrun[4], lrun[4];
#pragma unroll
  for (int r = 0; r < 4; ++r) { mrun[r] = -1e30f; lrun[r] = 0.f; }

  const int nch = (i0 >> 6) + 17;
  const int kvrow = tid >> 2;
  const int kvcol = (tid & 3) * 16;
  const int rrow = tid >> 1;
  const int rcol = (tid & 1) * 32;

  for (int c = 0; c < nch; ++c) {
    const int j0 = c * 64;
    __syncthreads();
    {
      const u16* kg = khB + (size_t)(j0 + kvrow) * DKk + kvcol;
      *(uint4*)&Ks[kvrow][kvcol] = *(const uint4*)kg;
      *(uint4*)&Ks[kvrow][kvcol + 8] = *(const uint4*)(kg + 8);
      const u16* vg = vtB + (size_t)kvrow * Tt + j0 + kvcol;
      *(uint4*)&Vs[kvrow][kvcol] = *(const uint4*)vg;
      *(uint4*)&Vs[kvrow][kvcol + 8] = *(const uint4*)(vg + 8);
      int grow = (i0 + j0 + 1023 + rrow) & 2047;
      const u16* rg = rhB + (size_t)grow * DKk + rcol;
      *(uint4*)&Re[rrow][rcol] = *(const uint4*)rg;
      *(uint4*)&Re[rrow][rcol + 8] = *(const uint4*)(rg + 8);
      *(uint4*)&Re[rrow][rcol + 16] = *(const uint4*)(rg + 16);
      *(uint4*)&Re[rrow][rcol + 24] = *(const uint4*)(rg + 24);
    }
    __syncthreads();

    // AC scores: (qh+u) . K
    f32x4 sacc[4];
#pragma unroll
    for (int ct = 0; ct < 4; ++ct) {
      f32x4 a = {};
      a = mfma16(qu0, *(const s16x8*)&Ks[ct * 16 + fr][fq * 8], a);
      a = mfma16(qu1, *(const s16x8*)&Ks[ct * 16 + fr][32 + fq * 8], a);
      sacc[ct] = a;
    }
    // G strip: (qh+v_bias) . Rh[(base+m)%T], m in [0,80)
#pragma unroll
    for (int mt = 0; mt < 5; ++mt) {
      f32x4 g = {};
      g = mfma16(qv0, *(const s16x8*)&Re[wave * 16 + mt * 16 + fr][fq * 8], g);
      g = mfma16(qv1, *(const s16x8*)&Re[wave * 16 + mt * 16 + fr][32 + fq * 8], g);
#pragma unroll
      for (int r = 0; r < 4; ++r) Gl[wave][fq * 4 + r][mt * 16 + fr] = g[r];
    }
    asm volatile("s_waitcnt lgkmcnt(0)" ::: "memory");

    // assemble scores + mask, online softmax
    float p[4][4];
    float cmax[4];
#pragma unroll
    for (int r = 0; r < 4; ++r) cmax[r] = -1e30f;
#pragma unroll
    for (int ct = 0; ct < 4; ++ct)
#pragma unroll
      for (int r = 0; r < 4; ++r) {
        int row = fq * 4 + r;
        float v = (sacc[ct][r] + Gl[wave][row][row + ct * 16 + fr]) * 0.125f;
        int gi = r0 + row, gj = j0 + ct * 16 + fr;
        if (gj > gi + MEMm) v = -1e30f;
        p[ct][r] = v;
        cmax[r] = fmaxf(cmax[r], v);
      }
#pragma unroll
    for (int r = 0; r < 4; ++r) {
      cmax[r] = fmaxf(cmax[r], __shfl_xor(cmax[r], 1));
      cmax[r] = fmaxf(cmax[r], __shfl_xor(cmax[r], 2));
      cmax[r] = fmaxf(cmax[r], __shfl_xor(cmax[r], 4));
      cmax[r] = fmaxf(cmax[r], __shfl_xor(cmax[r], 8));
    }
    float alpha[4];
#pragma unroll
    for (int r = 0; r < 4; ++r) {
      float mn = fmaxf(mrun[r], cmax[r]);
      alpha[r] = __expf(mrun[r] - mn);
      mrun[r] = mn;
    }
    float psum[4] = {0.f, 0.f, 0.f, 0.f};
#pragma unroll
    for (int ct = 0; ct < 4; ++ct)
#pragma unroll
      for (int r = 0; r < 4; ++r) {
        float e = __expf(p[ct][r] - mrun[r]);
        p[ct][r] = e;
        psum[r] += e;
      }
#pragma unroll
    for (int r = 0; r < 4; ++r) {
      psum[r] += __shfl_xor(psum[r], 1);
      psum[r] += __shfl_xor(psum[r], 2);
      psum[r] += __shfl_xor(psum[r], 4);
      psum[r] += __shfl_xor(psum[r], 8);
      lrun[r] = lrun[r] * alpha[r] + psum[r];
    }
#pragma unroll
    for (int t = 0; t < 4; ++t)
#pragma unroll
      for (int r = 0; r < 4; ++r) oacc[t][r] *= alpha[r];

    // P -> LDS (bf16), reload as A-fragments, PV MFMA
#pragma unroll
    for (int ct = 0; ct < 4; ++ct)
#pragma unroll
      for (int r = 0; r < 4; ++r)
        Pl[wave][fq * 4 + r][ct * 16 + fr] = f2bf(p[ct][r]);
    asm volatile("s_waitcnt lgkmcnt(0)" ::: "memory");
    s16x8 ap0 = *(const s16x8*)&Pl[wave][fr][fq * 8];
    s16x8 ap1 = *(const s16x8*)&Pl[wave][fr][32 + fq * 8];
#pragma unroll
    for (int t = 0; t < 4; ++t) {
      oacc[t] = mfma16(ap0, *(const s16x8*)&Vs[t * 16 + fr][fq * 8], oacc[t]);
      oacc[t] = mfma16(ap1, *(const s16x8*)&Vs[t * 16 + fr][32 + fq * 8], oacc[t]);
    }
  }

#pragma unroll
  for (int t = 0; t < 4; ++t)
#pragma unroll
    for (int r = 0; r < 4; ++r) {
      int row = fq * 4 + r;
      int gi = r0 + row;
      CONCAT[((size_t)b * Ss + gi) * Dd + h * DKk + t * 16 + fr] =
          oacc[t][r] / lrun[r];
    }
}

// ---------------------------------------------------------------------------
extern "C" void kernel_launch(void* const* d_in, const int* in_sizes, int n_in,
                              void* d_out, int out_size, void* d_ws,
                              size_t ws_size, hipStream_t stream) {
  const float* q  = (const float*)d_in[0];
  const float* k  = (const float*)d_in[1];
  const float* v  = (const float*)d_in[2];
  // d_in[3] = mask: analytic (j <= i + MEM), unused
  const float* u  = (const float*)d_in[4];
  const float* vb = (const float*)d_in[5];
  const float* Wq = (const float*)d_in[6];
  const float* Wk = (const float*)d_in[7];
  const float* Wv = (const float*)d_in[8];
  const float* Wr = (const float*)d_in[9];
  const float* Wo = (const float*)d_in[10];
  const float* R  = (const float*)d_in[11];

  char* ws = (char*)d_ws;
  u16* QU = (u16*)ws; ws += (size_t)Bb * Hh * Ss * DKk * 2;
  u16* QV = (u16*)ws; ws += (size_t)Bb * Hh * Ss * DKk * 2;
  u16* KH = (u16*)ws; ws += (size_t)Bb * Hh * Tt * DKk * 2;
  u16* VT = (u16*)ws; ws += (size_t)Bb * Hh * Tt * DKk * 2;
  u16* RH = (u16*)ws; ws += (size_t)Hh * Tt * DKk * 2;
  float* CONCAT = (float*)ws;

  gemm_nt<0><<<dim3(64, 16), 256, 0, stream>>>(q, Wq, QU, QV, u, vb);
  gemm_nt<1><<<dim3(128, 16), 256, 0, stream>>>(k, Wk, KH, nullptr, nullptr, nullptr);
  gemm_nt<2><<<dim3(128, 16), 256, 0, stream>>>(v, Wv, VT, nullptr, nullptr, nullptr);
  gemm_nt<3><<<dim3(32, 16), 256, 0, stream>>>(R, Wr, RH, nullptr, nullptr, nullptr);
  attn_kernel<<<dim3(16, 16, 4), 256, 0, stream>>>(QU, QV, KH, VT, RH, CONCAT);
  gemm_nt<4><<<dim3(64, 16), 256, 0, stream>>>(CONCAT, Wo, d_out, nullptr, nullptr, nullptr);
}

// Round 2
// 367.299 us; speedup vs baseline: 1.0914x; 1.0914x over previous
//
#include <hip/hip_runtime.h>
#include <stdint.h>

#define Ss   1024
#define MEMm 1024
#define Tt   2048
#define Dd   1024
#define Hh   16
#define DKk  64

typedef unsigned short u16;
using f32x4 = __attribute__((ext_vector_type(4))) float;
using s16x8 = __attribute__((ext_vector_type(8))) short;

__device__ __forceinline__ u16 f2bf(float x) {
  union { float f; uint32_t u; } c; c.f = x;
  uint32_t u = c.u;
  return (u16)((u + 0x7FFFu + ((u >> 16) & 1u)) >> 16);
}

__device__ __forceinline__ f32x4 mfma16(s16x8 a, s16x8 b, f32x4 c) {
  return __builtin_amdgcn_mfma_f32_16x16x32_bf16(a, b, c, 0, 0, 0);
}

__device__ __forceinline__ void gl_lds16(const u16* g, u16* l) {
  __builtin_amdgcn_global_load_lds(
      (const __attribute__((address_space(1))) uint32_t*)g,
      (__attribute__((address_space(3))) uint32_t*)l, 16, 0, 0);
}

// ---------------------------------------------------------------------------
// fp32 -> bf16 convert (vectorized, grid-stride)
// ---------------------------------------------------------------------------
__global__ __launch_bounds__(256)
void cvt_f32_bf16(const float* __restrict__ in, u16* __restrict__ out, int n8) {
  int i = blockIdx.x * 256 + threadIdx.x;
  const int stride = gridDim.x * 256;
  for (; i < n8; i += stride) {
    const float4* p = (const float4*)(in + (size_t)i * 8);
    float4 a = p[0], bq = p[1];
    uint4 o;
    o.x = f2bf(a.x) | ((unsigned)f2bf(a.y) << 16);
    o.y = f2bf(a.z) | ((unsigned)f2bf(a.w) << 16);
    o.z = f2bf(bq.x) | ((unsigned)f2bf(bq.y) << 16);
    o.w = f2bf(bq.z) | ((unsigned)f2bf(bq.w) << 16);
    *(uint4*)(out + (size_t)i * 8) = o;
  }
}

// ---------------------------------------------------------------------------
// bf16 NT GEMM, m97 structure: 128x128 tile, 4 waves, BK=32,
// global_load_lds width-16 staging, 8 ds_read_b128 + 16 MFMA per K-step.
// Y[n,m] = sum_k X[n,k] * W[m,k]. Epilogues as in round 1.
// ---------------------------------------------------------------------------
template <int EPI>
__global__ __launch_bounds__(256)
void gemm128(const u16* __restrict__ X, const u16* __restrict__ W,
             void* __restrict__ O1, void* __restrict__ O2,
             const float* __restrict__ b1, const float* __restrict__ b2,
             int rowOff) {
  __shared__ u16 As[128 * 32];
  __shared__ u16 Bs[128 * 32];
  const int tid = threadIdx.x;
  const int lane = tid & 63, wave = tid >> 6;
  const int fr = lane & 15, fq = lane >> 4;
  const int n0 = blockIdx.x * 128, m0 = blockIdx.y * 128;
  const int wr = (wave >> 1) * 64, wc = (wave & 1) * 64;
  f32x4 acc[4][4] = {};

  const int lrow = lane >> 2;        // 0..15
  const int lcol = (lane & 3) * 8;   // 0,8,16,24
  const u16* xg0 = X + (size_t)(n0 + wave * 16 + lrow) * Dd + lcol;
  const u16* xg1 = X + (size_t)(n0 + 64 + wave * 16 + lrow) * Dd + lcol;
  const u16* wg0 = W + (size_t)(m0 + wave * 16 + lrow) * Dd + lcol;
  const u16* wg1 = W + (size_t)(m0 + 64 + wave * 16 + lrow) * Dd + lcol;
  u16* la0 = &As[(wave * 16) * 32];
  u16* la1 = &As[(64 + wave * 16) * 32];
  u16* lb0 = &Bs[(wave * 16) * 32];
  u16* lb1 = &Bs[(64 + wave * 16) * 32];

  for (int k0 = 0; k0 < Dd; k0 += 32) {
    gl_lds16(xg0 + k0, la0);
    gl_lds16(xg1 + k0, la1);
    gl_lds16(wg0 + k0, lb0);
    gl_lds16(wg1 + k0, lb1);
    __syncthreads();
    s16x8 af[4], bfv[4];
#pragma unroll
    for (int i = 0; i < 4; ++i)
      af[i] = *(const s16x8*)&As[(wr + i * 16 + fr) * 32 + fq * 8];
#pragma unroll
    for (int j = 0; j < 4; ++j)
      bfv[j] = *(const s16x8*)&Bs[(wc + j * 16 + fr) * 32 + fq * 8];
#pragma unroll
    for (int i = 0; i < 4; ++i)
#pragma unroll
      for (int j = 0; j < 4; ++j)
        acc[i][j] = mfma16(af[i], bfv[j], acc[i][j]);
    __syncthreads();
  }

#pragma unroll
  for (int i = 0; i < 4; ++i)
#pragma unroll
    for (int j = 0; j < 4; ++j) {
      if constexpr (EPI == 2) {
        const int grow = rowOff + n0 + wr + i * 16 + fq * 4;  // 4 consecutive t
        const int m = m0 + wc + j * 16 + fr;
        const int bb = grow >> 11, t = grow & 2047;
        const int hh = m >> 6, dk = m & 63;
        ushort4 pk;
        pk.x = f2bf(acc[i][j][0]); pk.y = f2bf(acc[i][j][1]);
        pk.z = f2bf(acc[i][j][2]); pk.w = f2bf(acc[i][j][3]);
        *(ushort4*)&((u16*)O1)[(((size_t)(bb * Hh + hh) * DKk + dk) << 11) + t] = pk;
      } else {
#pragma unroll
        for (int r = 0; r < 4; ++r) {
          const int n = rowOff + n0 + wr + i * 16 + fq * 4 + r;
          const int m = m0 + wc + j * 16 + fr;
          const float y = acc[i][j][r];
          if constexpr (EPI == 0) {
            const int bb = n >> 10, s = n & 1023, hh = m >> 6, dk = m & 63;
            const size_t idx = ((size_t)(bb * Hh + hh) * Ss + s) * DKk + dk;
            ((u16*)O1)[idx] = f2bf(y + b1[m]);
            ((u16*)O2)[idx] = f2bf(y + b2[m]);
          } else if constexpr (EPI == 1) {
            const int bb = n >> 11, t = n & 2047, hh = m >> 6, dk = m & 63;
            ((u16*)O1)[((size_t)(bb * Hh + hh) * Tt + t) * DKk + dk] = f2bf(y);
          } else if constexpr (EPI == 3) {
            const int hh = m >> 6, dk = m & 63;
            ((u16*)O1)[((size_t)hh * Tt + n) * DKk + dk] = f2bf(y);
          } else {
            ((float*)O1)[(size_t)n * Dd + m] = y;
          }
        }
      }
    }
}

// ---------------------------------------------------------------------------
// Fused TXL attention v2: 512 threads = 8 waves, 128 Q-rows/block.
// - BD diagonal gather via __shfl (no Gl LDS, no 4-way conflicts)
// - AC MFMAs accumulate directly into gathered BD
// - circular 256-row Re buffer: 64 new rows/chunk (first chunk: 192)
// - reg-prefetch of K/V/Re for chunk c+1 during compute of chunk c
// - XCD-aware work remap: 8 blocks sharing (b,h) -> same XCD L2
// - writes CONCAT as bf16
// ---------------------------------------------------------------------------
__global__ __launch_bounds__(512)
void attn2(const u16* __restrict__ QU, const u16* __restrict__ QV,
           const u16* __restrict__ KH, const u16* __restrict__ VT,
           const u16* __restrict__ RH, u16* __restrict__ CONCAT) {
  __shared__ u16 Ks[64][72];
  __shared__ u16 Vs[64][72];
  __shared__ u16 RB[256][72];
  __shared__ u16 Pl[8][16][72];

  const int tid = threadIdx.x;
  const int wave = tid >> 6, lane = tid & 63;
  const int fr = lane & 15, fq = lane >> 4;

  // work remap: wid -> (bx, b, h) such that all 8 bx of one (b,h) share an XCD
  const int wid = blockIdx.x;
  const int bx = (wid >> 3) & 7;
  const int bh = (wid & 7) | ((wid >> 6) << 3);
  const int h = bh & 15, b = bh >> 4;
  const int i0 = bx * 128;
  const int r0 = i0 + wave * 16;

  const u16* quB = QU + (size_t)(b * Hh + h) * Ss * DKk;
  const u16* qvB = QV + (size_t)(b * Hh + h) * Ss * DKk;
  const u16* khB = KH + (size_t)(b * Hh + h) * Tt * DKk;
  const u16* vtB = VT + (size_t)(b * Hh + h) * DKk * Tt;
  const u16* rhB = RH + (size_t)h * Tt * DKk;

  const s16x8 qu0 = *(const s16x8*)(quB + (size_t)(r0 + fr) * DKk + fq * 8);
  const s16x8 qu1 = *(const s16x8*)(quB + (size_t)(r0 + fr) * DKk + 32 + fq * 8);
  const s16x8 qv0 = *(const s16x8*)(qvB + (size_t)(r0 + fr) * DKk + fq * 8);
  const s16x8 qv1 = *(const s16x8*)(qvB + (size_t)(r0 + fr) * DKk + 32 + fq * 8);

  const int base = (i0 + 1023) & 2047;
  const int krow = tid >> 3;        // 0..63
  const int kcol = (tid & 7) * 8;   // 0..56

  // prologue: Re rows a in [0,192)
#pragma unroll
  for (int rb = 0; rb < 3; ++rb) {
    const int a = rb * 64 + krow;
    *(uint4*)&RB[a][kcol] =
        *(const uint4*)(rhB + (size_t)((base + a) & 2047) * DKk + kcol);
  }
  uint4 kx = *(const uint4*)(khB + (size_t)krow * DKk + kcol);
  uint4 vx = *(const uint4*)(vtB + (size_t)krow * Tt + kcol);
  uint4 rx = {};

  f32x4 oacc[4] = {};
  float mrun[4], lrun[4];
#pragma unroll
  for (int r = 0; r < 4; ++r) { mrun[r] = -1e30f; lrun[r] = 0.f; }

  const int nch = (i0 >> 6) + 18;
  for (int c = 0; c < nch; ++c) {
    const int j0 = c * 64;
    __syncthreads();  // previous compute done reading Ks/Vs
    *(uint4*)&Ks[krow][kcol] = kx;
    *(uint4*)&Vs[krow][kcol] = vx;
    if (c > 0) *(uint4*)&RB[(j0 + 128 + krow) & 255][kcol] = rx;
    __syncthreads();
    if (c + 1 < nch) {  // prefetch chunk c+1 into regs; latency hides under compute
      kx = *(const uint4*)(khB + (size_t)(j0 + 64 + krow) * DKk + kcol);
      vx = *(const uint4*)(vtB + (size_t)krow * Tt + (j0 + 64) + kcol);
      rx = *(const uint4*)(rhB + (size_t)((base + j0 + 192 + krow) & 2047) * DKk + kcol);
    }

    // G strip: G[row, m] = QV[r0+row] . Rh[(base + 64c + 16w + m) % T], m in [0,80)
    f32x4 g[5];
    __builtin_amdgcn_s_setprio(1);
#pragma unroll
    for (int mt = 0; mt < 5; ++mt) {
      const int rr = (j0 + wave * 16 + mt * 16 + fr) & 255;
      f32x4 t = {};
      t = mfma16(qv0, *(const s16x8*)&RB[rr][fq * 8], t);
      t = mfma16(qv1, *(const s16x8*)&RB[rr][32 + fq * 8], t);
      g[mt] = t;
    }
    __builtin_amdgcn_s_setprio(0);

    // BD[row, q] = G[row, row+q]: intra-fq-group shuffle + carry select
    f32x4 pacc[4];
#pragma unroll
    for (int r = 0; r < 4; ++r) {
      const int s = fq * 4 + r + fr;            // row + fr
      const int src = fq * 16 + (s & 15);
      const bool carry = s >= 16;
      const float s0 = __shfl(g[0][r], src);
      const float s1 = __shfl(g[1][r], src);
      const float s2 = __shfl(g[2][r], src);
      const float s3 = __shfl(g[3][r], src);
      const float s4 = __shfl(g[4][r], src);
      pacc[0][r] = carry ? s1 : s0;
      pacc[1][r] = carry ? s2 : s1;
      pacc[2][r] = carry ? s3 : s2;
      pacc[3][r] = carry ? s4 : s3;
    }

    // AC: accumulate (qh+u).K directly into BD
    __builtin_amdgcn_s_setprio(1);
#pragma unroll
    for (int ct = 0; ct < 4; ++ct) {
      pacc[ct] = mfma16(qu0, *(const s16x8*)&Ks[ct * 16 + fr][fq * 8], pacc[ct]);
      pacc[ct] = mfma16(qu1, *(const s16x8*)&Ks[ct * 16 + fr][32 + fq * 8], pacc[ct]);
    }
    __builtin_amdgcn_s_setprio(0);

    // scale + (wave-uniform-skipped) mask
    if (j0 + 63 > r0 + MEMm) {
#pragma unroll
      for (int ct = 0; ct < 4; ++ct)
#pragma unroll
        for (int r = 0; r < 4; ++r) {
          const int gi = r0 + fq * 4 + r, gj = j0 + ct * 16 + fr;
          const float vv = pacc[ct][r] * 0.125f;
          pacc[ct][r] = (gj > gi + MEMm) ? -1e30f : vv;
        }
    } else {
#pragma unroll
      for (int ct = 0; ct < 4; ++ct)
#pragma unroll
        for (int r = 0; r < 4; ++r) pacc[ct][r] *= 0.125f;
    }

    // online softmax (reduce over fr within fq group)
    float cmax[4];
#pragma unroll
    for (int r = 0; r < 4; ++r)
      cmax[r] = fmaxf(fmaxf(pacc[0][r], pacc[1][r]), fmaxf(pacc[2][r], pacc[3][r]));
#pragma unroll
    for (int r = 0; r < 4; ++r) {
      cmax[r] = fmaxf(cmax[r], __shfl_xor(cmax[r], 1));
      cmax[r] = fmaxf(cmax[r], __shfl_xor(cmax[r], 2));
      cmax[r] = fmaxf(cmax[r], __shfl_xor(cmax[r], 4));
      cmax[r] = fmaxf(cmax[r], __shfl_xor(cmax[r], 8));
    }
    float alpha[4];
#pragma unroll
    for (int r = 0; r < 4; ++r) {
      const float mn = fmaxf(mrun[r], cmax[r]);
      alpha[r] = __expf(mrun[r] - mn);
      mrun[r] = mn;
    }
    float psum[4] = {0.f, 0.f, 0.f, 0.f};
#pragma unroll
    for (int ct = 0; ct < 4; ++ct)
#pragma unroll
      for (int r = 0; r < 4; ++r) {
        const float e = __expf(pacc[ct][r] - mrun[r]);
        pacc[ct][r] = e;
        psum[r] += e;
      }
#pragma unroll
    for (int r = 0; r < 4; ++r) {
      psum[r] += __shfl_xor(psum[r], 1);
      psum[r] += __shfl_xor(psum[r], 2);
      psum[r] += __shfl_xor(psum[r], 4);
      psum[r] += __shfl_xor(psum[r], 8);
      lrun[r] = lrun[r] * alpha[r] + psum[r];
    }
#pragma unroll
    for (int t = 0; t < 4; ++t)
#pragma unroll
      for (int r = 0; r < 4; ++r) oacc[t][r] *= alpha[r];

    // P -> LDS (per-wave) -> A-fragments, PV MFMA
#pragma unroll
    for (int ct = 0; ct < 4; ++ct)
#pragma unroll
      for (int r = 0; r < 4; ++r)
        Pl[wave][fq * 4 + r][ct * 16 + fr] = f2bf(pacc[ct][r]);
    asm volatile("s_waitcnt lgkmcnt(0)" ::: "memory");
    __builtin_amdgcn_sched_barrier(0);
    const s16x8 ap0 = *(const s16x8*)&Pl[wave][fr][fq * 8];
    const s16x8 ap1 = *(const s16x8*)&Pl[wave][fr][32 + fq * 8];
    __builtin_amdgcn_s_setprio(1);
#pragma unroll
    for (int t = 0; t < 4; ++t) {
      oacc[t] = mfma16(ap0, *(const s16x8*)&Vs[t * 16 + fr][fq * 8], oacc[t]);
      oacc[t] = mfma16(ap1, *(const s16x8*)&Vs[t * 16 + fr][32 + fq * 8], oacc[t]);
    }
    __builtin_amdgcn_s_setprio(0);
  }

#pragma unroll
  for (int t = 0; t < 4; ++t)
#pragma unroll
    for (int r = 0; r < 4; ++r) {
      const int gi = r0 + fq * 4 + r;
      CONCAT[((size_t)b * Ss + gi) * Dd + h * DKk + t * 16 + fr] =
          f2bf(oacc[t][r] / lrun[r]);
    }
}

// ---------------------------------------------------------------------------
extern "C" void kernel_launch(void* const* d_in, const int* in_sizes, int n_in,
                              void* d_out, int out_size, void* d_ws,
                              size_t ws_size, hipStream_t stream) {
  (void)in_sizes; (void)n_in; (void)out_size; (void)ws_size;
  const float* q  = (const float*)d_in[0];
  const float* k  = (const float*)d_in[1];
  const float* v  = (const float*)d_in[2];
  // d_in[3] = mask: analytic (j <= i + MEM), unused
  const float* u  = (const float*)d_in[4];
  const float* vb = (const float*)d_in[5];
  const float* Wq = (const float*)d_in[6];
  const float* Wk = (const float*)d_in[7];
  const float* Wv = (const float*)d_in[8];
  const float* Wr = (const float*)d_in[9];
  const float* Wo = (const float*)d_in[10];
  const float* R  = (const float*)d_in[11];

  char* ws = (char*)d_ws;
  u16* QU  = (u16*)ws; ws += 8388608;   // [B,H,S,DK] bf16
  u16* QV  = (u16*)ws; ws += 8388608;
  u16* KH  = (u16*)ws; ws += 16777216;  // [B,H,T,DK]
  u16* VT  = (u16*)ws; ws += 16777216;  // [B,H,DK,T]
  u16* RH  = (u16*)ws; ws += 4194304;   // [H,T,DK]
  u16* S0a = (u16*)ws; ws += 8388608;   // shared bf16 data scratch (also CONCAT)
  u16* S0w = (u16*)ws;                  // shared bf16 weight scratch (2 MB)

  auto cvt = [&](const float* src, u16* dst, size_t n) {
    const int n8 = (int)(n >> 3);
    int blocks = (n8 + 255) >> 8;
    if (blocks > 2048) blocks = 2048;
    cvt_f32_bf16<<<blocks, 256, 0, stream>>>(src, dst, n8);
  };
  const size_t M1 = (size_t)1 << 20, M2 = (size_t)2 << 20, M4 = (size_t)4 << 20;

  cvt(Wq, S0w, M1); cvt(q, S0a, M4);
  gemm128<0><<<dim3(32, 8), 256, 0, stream>>>(S0a, S0w, QU, QV, u, vb, 0);
  cvt(Wk, S0w, M1); cvt(k, S0a, M4);
  gemm128<1><<<dim3(32, 8), 256, 0, stream>>>(S0a, S0w, KH, nullptr, nullptr, nullptr, 0);
  cvt(k + M4, S0a, M4);
  gemm128<1><<<dim3(32, 8), 256, 0, stream>>>(S0a, S0w, KH, nullptr, nullptr, nullptr, 4096);
  cvt(Wv, S0w, M1); cvt(v, S0a, M4);
  gemm128<2><<<dim3(32, 8), 256, 0, stream>>>(S0a, S0w, VT, nullptr, nullptr, nullptr, 0);
  cvt(v + M4, S0a, M4);
  gemm128<2><<<dim3(32, 8), 256, 0, stream>>>(S0a, S0w, VT, nullptr, nullptr, nullptr, 4096);
  cvt(Wr, S0w, M1); cvt(R, S0a, M2);
  gemm128<3><<<dim3(16, 8), 256, 0, stream>>>(S0a, S0w, RH, nullptr, nullptr, nullptr, 0);
  cvt(Wo, S0w, M1);
  attn2<<<512, 512, 0, stream>>>(QU, QV, KH, VT, RH, S0a);
  gemm128<4><<<dim3(32, 8), 256, 0, stream>>>(S0a, S0w, d_out, nullptr, nullptr, nullptr, 0);
}

// Round 3
// 298.709 us; speedup vs baseline: 1.3421x; 1.2296x over previous
//
#include <hip/hip_runtime.h>
#include <hip/hip_bf16.h>
#include <stdint.h>

#define Ss   1024
#define MEMm 1024
#define Tt   2048
#define Dd   1024
#define Hh   16
#define DKk  64

typedef unsigned short u16;
using f32x4 = __attribute__((ext_vector_type(4))) float;
using s16x8 = __attribute__((ext_vector_type(8))) short;

__device__ __forceinline__ u16 f2bf(float x) {
  __hip_bfloat16 h = __float2bfloat16(x);
  return *(reinterpret_cast<u16*>(&h));
}
__device__ __forceinline__ uint32_t pk2(float lo, float hi) {
  return (uint32_t)f2bf(lo) | ((uint32_t)f2bf(hi) << 16);
}
__device__ __forceinline__ f32x4 mfma16(s16x8 a, s16x8 b, f32x4 c) {
  return __builtin_amdgcn_mfma_f32_16x16x32_bf16(a, b, c, 0, 0, 0);
}
__device__ __forceinline__ void gl_lds16(const u16* g, u16* l) {
  __builtin_amdgcn_global_load_lds(
      (const __attribute__((address_space(1))) uint32_t*)g,
      (__attribute__((address_space(3))) uint32_t*)l, 16, 0, 0);
}

// ---------------------------------------------------------------------------
// Convert the 5 weight matrices (1M fp32 each) to bf16 in one dispatch.
// grid = (512, 5); each thread converts 8 elements.
// ---------------------------------------------------------------------------
__global__ __launch_bounds__(256)
void cvt5(const float* __restrict__ w0, const float* __restrict__ w1,
          const float* __restrict__ w2, const float* __restrict__ w3,
          const float* __restrict__ w4, u16* __restrict__ dst) {
  const float* s;
  switch (blockIdx.y) {
    case 0: s = w0; break; case 1: s = w1; break; case 2: s = w2; break;
    case 3: s = w3; break; default: s = w4; break;
  }
  const int idx = blockIdx.x * 256 + threadIdx.x;
  const float4* p = (const float4*)(s + (size_t)idx * 8);
  const float4 a = p[0], bq = p[1];
  uint4 o;
  o.x = pk2(a.x, a.y);  o.y = pk2(a.z, a.w);
  o.z = pk2(bq.x, bq.y); o.w = pk2(bq.z, bq.w);
  *(uint4*)(dst + ((size_t)blockIdx.y << 20) + (size_t)idx * 8) = o;
}

// ---------------------------------------------------------------------------
// Fused Q/K/V/R projection GEMM, one dispatch (1408 blocks).
// A-side: fp32 input, reg-staged with inline bf16 cvt -> LDS.
// B-side: bf16 weights via global_load_lds width-16.
// 128x128 tile, 4 waves, BK=32. Epilogue selected by uniform proj id.
// ---------------------------------------------------------------------------
__global__ __launch_bounds__(256)
void gemm_qkvr(const float* __restrict__ Xq, const float* __restrict__ Xk,
               const float* __restrict__ Xv, const float* __restrict__ Xr,
               const u16* __restrict__ Wb,
               u16* __restrict__ QU, u16* __restrict__ QV,
               u16* __restrict__ KH, u16* __restrict__ VT,
               u16* __restrict__ RH,
               const float* __restrict__ ub, const float* __restrict__ vbb) {
  __shared__ u16 As[128 * 32];
  __shared__ u16 Bs[128 * 32];
  const int bid = blockIdx.x;
  int proj, t;
  const float* X;
  if (bid < 256)       { proj = 0; t = bid;        X = Xq; }
  else if (bid < 768)  { proj = 1; t = bid - 256;  X = Xk; }
  else if (bid < 1280) { proj = 2; t = bid - 768;  X = Xv; }
  else                 { proj = 3; t = bid - 1280; X = Xr; }
  const u16* W = Wb + ((size_t)proj << 20);
  const int n0 = (t >> 3) * 128, m0 = (t & 7) * 128;

  const int tid = threadIdx.x;
  const int lane = tid & 63, wave = tid >> 6;
  const int fr = lane & 15, fq = lane >> 4;
  const int wr = (wave >> 1) * 64, wc = (wave & 1) * 64;
  f32x4 acc[4][4] = {};

  // A staging: row = tid>>1 (0..127), 16-col half = (tid&1)*16
  const int arow = tid >> 1, acol = (tid & 1) * 16;
  const float* xg = X + (size_t)(n0 + arow) * Dd + acol;
  u16* aw = &As[arow * 32 + acol];

  // B staging (global_load_lds): as m97
  const int lrow = lane >> 2, lcol = (lane & 3) * 8;
  const u16* wg0 = W + (size_t)(m0 + wave * 16 + lrow) * Dd + lcol;
  const u16* wg1 = W + (size_t)(m0 + 64 + wave * 16 + lrow) * Dd + lcol;
  u16* lb0 = &Bs[(wave * 16) * 32];
  u16* lb1 = &Bs[(64 + wave * 16) * 32];

  for (int k0 = 0; k0 < Dd; k0 += 32) {
    const float4 f0 = *(const float4*)(xg + k0);
    const float4 f1 = *(const float4*)(xg + k0 + 4);
    const float4 f2 = *(const float4*)(xg + k0 + 8);
    const float4 f3 = *(const float4*)(xg + k0 + 12);
    __syncthreads();  // previous tile fully consumed
    gl_lds16(wg0 + k0, lb0);
    gl_lds16(wg1 + k0, lb1);
    uint4 p0, p1;
    p0.x = pk2(f0.x, f0.y); p0.y = pk2(f0.z, f0.w);
    p0.z = pk2(f1.x, f1.y); p0.w = pk2(f1.z, f1.w);
    p1.x = pk2(f2.x, f2.y); p1.y = pk2(f2.z, f2.w);
    p1.z = pk2(f3.x, f3.y); p1.w = pk2(f3.z, f3.w);
    *(uint4*)aw = p0;
    *(uint4*)(aw + 8) = p1;
    __syncthreads();  // staging visible (barrier drains vmcnt incl. gl_lds)
    s16x8 af[4], bfv[4];
#pragma unroll
    for (int i = 0; i < 4; ++i)
      af[i] = *(const s16x8*)&As[(wr + i * 16 + fr) * 32 + fq * 8];
#pragma unroll
    for (int j = 0; j < 4; ++j)
      bfv[j] = *(const s16x8*)&Bs[(wc + j * 16 + fr) * 32 + fq * 8];
#pragma unroll
    for (int i = 0; i < 4; ++i)
#pragma unroll
      for (int j = 0; j < 4; ++j)
        acc[i][j] = mfma16(af[i], bfv[j], acc[i][j]);
  }

#pragma unroll
  for (int i = 0; i < 4; ++i)
#pragma unroll
    for (int j = 0; j < 4; ++j) {
      if (proj == 2) {  // VT: [B,H,DK,T] bf16, 4 consecutive t -> ushort4
        const int grow = n0 + wr + i * 16 + fq * 4;
        const int m = m0 + wc + j * 16 + fr;
        const int bb = grow >> 11, t2 = grow & 2047;
        const int hh = m >> 6, dk = m & 63;
        ushort4 pk4;
        pk4.x = f2bf(acc[i][j][0]); pk4.y = f2bf(acc[i][j][1]);
        pk4.z = f2bf(acc[i][j][2]); pk4.w = f2bf(acc[i][j][3]);
        *(ushort4*)&VT[(((size_t)(bb * Hh + hh) * DKk + dk) << 11) + t2] = pk4;
      } else {
#pragma unroll
        for (int r = 0; r < 4; ++r) {
          const int n = n0 + wr + i * 16 + fq * 4 + r;
          const int m = m0 + wc + j * 16 + fr;
          const float y = acc[i][j][r];
          if (proj == 0) {
            const int bb = n >> 10, s = n & 1023, hh = m >> 6, dk = m & 63;
            const size_t idx = ((size_t)(bb * Hh + hh) * Ss + s) * DKk + dk;
            QU[idx] = f2bf(y + ub[m]);
            QV[idx] = f2bf(y + vbb[m]);
          } else if (proj == 1) {
            const int bb = n >> 11, t2 = n & 2047, hh = m >> 6, dk = m & 63;
            KH[((size_t)(bb * Hh + hh) * Tt + t2) * DKk + dk] = f2bf(y);
          } else {
            const int hh = m >> 6, dk = m & 63;
            RH[((size_t)hh * Tt + n) * DKk + dk] = f2bf(y);
          }
        }
      }
    }
}

// ---------------------------------------------------------------------------
// O-projection: pure-bf16 m97 GEMM (gl_lds both sides), fp32 output.
// ---------------------------------------------------------------------------
__global__ __launch_bounds__(256)
void gemm_o(const u16* __restrict__ X, const u16* __restrict__ W,
            float* __restrict__ O) {
  __shared__ u16 As[128 * 32];
  __shared__ u16 Bs[128 * 32];
  const int tid = threadIdx.x;
  const int lane = tid & 63, wave = tid >> 6;
  const int fr = lane & 15, fq = lane >> 4;
  const int n0 = blockIdx.x * 128, m0 = blockIdx.y * 128;
  const int wr = (wave >> 1) * 64, wc = (wave & 1) * 64;
  f32x4 acc[4][4] = {};

  const int lrow = lane >> 2, lcol = (lane & 3) * 8;
  const u16* xg0 = X + (size_t)(n0 + wave * 16 + lrow) * Dd + lcol;
  const u16* xg1 = X + (size_t)(n0 + 64 + wave * 16 + lrow) * Dd + lcol;
  const u16* wg0 = W + (size_t)(m0 + wave * 16 + lrow) * Dd + lcol;
  const u16* wg1 = W + (size_t)(m0 + 64 + wave * 16 + lrow) * Dd + lcol;
  u16* la0 = &As[(wave * 16) * 32];
  u16* la1 = &As[(64 + wave * 16) * 32];
  u16* lb0 = &Bs[(wave * 16) * 32];
  u16* lb1 = &Bs[(64 + wave * 16) * 32];

  for (int k0 = 0; k0 < Dd; k0 += 32) {
    gl_lds16(xg0 + k0, la0);
    gl_lds16(xg1 + k0, la1);
    gl_lds16(wg0 + k0, lb0);
    gl_lds16(wg1 + k0, lb1);
    __syncthreads();
    s16x8 af[4], bfv[4];
#pragma unroll
    for (int i = 0; i < 4; ++i)
      af[i] = *(const s16x8*)&As[(wr + i * 16 + fr) * 32 + fq * 8];
#pragma unroll
    for (int j = 0; j < 4; ++j)
      bfv[j] = *(const s16x8*)&Bs[(wc + j * 16 + fr) * 32 + fq * 8];
#pragma unroll
    for (int i = 0; i < 4; ++i)
#pragma unroll
      for (int j = 0; j < 4; ++j)
        acc[i][j] = mfma16(af[i], bfv[j], acc[i][j]);
    __syncthreads();
  }

#pragma unroll
  for (int i = 0; i < 4; ++i)
#pragma unroll
    for (int j = 0; j < 4; ++j)
#pragma unroll
      for (int r = 0; r < 4; ++r) {
        const int n = n0 + wr + i * 16 + fq * 4 + r;
        const int m = m0 + wc + j * 16 + fr;
        O[(size_t)n * Dd + m] = acc[i][j][r];
      }
}

// ---------------------------------------------------------------------------
// Fused TXL attention v3: as v2 plus
//  - log2-domain softmax (exp2f, scale folded)
//  - ones-row V trick: PV MFMA accumulates the softmax denominator (no psum
//    shuffle reduction; denominator read once at the end via 4 shuffles)
//  - heavy-tiles-first block order
// ---------------------------------------------------------------------------
__global__ __launch_bounds__(512)
void attn2(const u16* __restrict__ QU, const u16* __restrict__ QV,
           const u16* __restrict__ KH, const u16* __restrict__ VT,
           const u16* __restrict__ RH, u16* __restrict__ CONCAT) {
  __shared__ u16 Ks[64][72];
  __shared__ u16 Vs[80][72];   // rows 64..79: ones row (64) + zeros
  __shared__ u16 RB[256][72];
  __shared__ u16 Pl[8][16][72];

  const int tid = threadIdx.x;
  const int wave = tid >> 6, lane = tid & 63;
  const int fr = lane & 15, fq = lane >> 4;

  const int wid = blockIdx.x;
  const int bx = 7 - ((wid >> 3) & 7);  // heavy tiles dispatch first
  const int bh = (wid & 7) | ((wid >> 6) << 3);
  const int h = bh & 15, b = bh >> 4;
  const int i0 = bx * 128;
  const int r0 = i0 + wave * 16;

  const u16* quB = QU + (size_t)(b * Hh + h) * Ss * DKk;
  const u16* qvB = QV + (size_t)(b * Hh + h) * Ss * DKk;
  const u16* khB = KH + (size_t)(b * Hh + h) * Tt * DKk;
  const u16* vtB = VT + (size_t)(b * Hh + h) * DKk * Tt;
  const u16* rhB = RH + (size_t)h * Tt * DKk;

  // static rows of Vs: row 64 = 1.0 over key cols, rows 65..79 = 0
  for (int idx = tid; idx < 16 * 72; idx += 512) {
    const int rr = idx / 72, cc = idx - rr * 72;
    Vs[64 + rr][cc] = (rr == 0 && cc < 64) ? (u16)0x3F80 : (u16)0;
  }

  const s16x8 qu0 = *(const s16x8*)(quB + (size_t)(r0 + fr) * DKk + fq * 8);
  const s16x8 qu1 = *(const s16x8*)(quB + (size_t)(r0 + fr) * DKk + 32 + fq * 8);
  const s16x8 qv0 = *(const s16x8*)(qvB + (size_t)(r0 + fr) * DKk + fq * 8);
  const s16x8 qv1 = *(const s16x8*)(qvB + (size_t)(r0 + fr) * DKk + 32 + fq * 8);

  const int base = (i0 + 1023) & 2047;
  const int krow = tid >> 3;        // 0..63
  const int kcol = (tid & 7) * 8;   // 0..56

#pragma unroll
  for (int rb = 0; rb < 3; ++rb) {
    const int a = rb * 64 + krow;
    *(uint4*)&RB[a][kcol] =
        *(const uint4*)(rhB + (size_t)((base + a) & 2047) * DKk + kcol);
  }
  uint4 kx = *(const uint4*)(khB + (size_t)krow * DKk + kcol);
  uint4 vx = *(const uint4*)(vtB + (size_t)krow * Tt + kcol);
  uint4 rx = {};

  f32x4 oacc[4] = {};
  f32x4 oacc2 = {};  // denominator accumulator (ones column, fr==0 lanes)
  float mrun[4];
#pragma unroll
  for (int r = 0; r < 4; ++r) mrun[r] = -1e30f;

  const float SC = 0.18033688011f;  // 0.125 * log2(e)

  const int nch = (i0 >> 6) + 18;
  for (int c = 0; c < nch; ++c) {
    const int j0 = c * 64;
    __syncthreads();
    *(uint4*)&Ks[krow][kcol] = kx;
    *(uint4*)&Vs[krow][kcol] = vx;
    if (c > 0) *(uint4*)&RB[(j0 + 128 + krow) & 255][kcol] = rx;
    __syncthreads();
    if (c + 1 < nch) {
      kx = *(const uint4*)(khB + (size_t)(j0 + 64 + krow) * DKk + kcol);
      vx = *(const uint4*)(vtB + (size_t)krow * Tt + (j0 + 64) + kcol);
      rx = *(const uint4*)(rhB + (size_t)((base + j0 + 192 + krow) & 2047) * DKk + kcol);
    }

    // G strip
    f32x4 g[5];
    __builtin_amdgcn_s_setprio(1);
#pragma unroll
    for (int mt = 0; mt < 5; ++mt) {
      const int rr = (j0 + wave * 16 + mt * 16 + fr) & 255;
      f32x4 tacc = {};
      tacc = mfma16(qv0, *(const s16x8*)&RB[rr][fq * 8], tacc);
      tacc = mfma16(qv1, *(const s16x8*)&RB[rr][32 + fq * 8], tacc);
      g[mt] = tacc;
    }
    __builtin_amdgcn_s_setprio(0);

    // BD diagonal gather
    f32x4 pacc[4];
#pragma unroll
    for (int r = 0; r < 4; ++r) {
      const int s = fq * 4 + r + fr;
      const int src = fq * 16 + (s & 15);
      const bool carry = s >= 16;
      const float s0 = __shfl(g[0][r], src);
      const float s1 = __shfl(g[1][r], src);
      const float s2 = __shfl(g[2][r], src);
      const float s3 = __shfl(g[3][r], src);
      const float s4 = __shfl(g[4][r], src);
      pacc[0][r] = carry ? s1 : s0;
      pacc[1][r] = carry ? s2 : s1;
      pacc[2][r] = carry ? s3 : s2;
      pacc[3][r] = carry ? s4 : s3;
    }

    // AC accumulate into BD
    __builtin_amdgcn_s_setprio(1);
#pragma unroll
    for (int ct = 0; ct < 4; ++ct) {
      pacc[ct] = mfma16(qu0, *(const s16x8*)&Ks[ct * 16 + fr][fq * 8], pacc[ct]);
      pacc[ct] = mfma16(qu1, *(const s16x8*)&Ks[ct * 16 + fr][32 + fq * 8], pacc[ct]);
    }
    __builtin_amdgcn_s_setprio(0);

    // scale to log2 domain + mask
    if (j0 + 63 > r0 + MEMm) {
#pragma unroll
      for (int ct = 0; ct < 4; ++ct)
#pragma unroll
        for (int r = 0; r < 4; ++r) {
          const int gi = r0 + fq * 4 + r, gj = j0 + ct * 16 + fr;
          const float vv = pacc[ct][r] * SC;
          pacc[ct][r] = (gj > gi + MEMm) ? -1e30f : vv;
        }
    } else {
#pragma unroll
      for (int ct = 0; ct < 4; ++ct)
#pragma unroll
        for (int r = 0; r < 4; ++r) pacc[ct][r] *= SC;
    }

    // online softmax (log2 domain), row max over fr lanes
    float cmax[4];
#pragma unroll
    for (int r = 0; r < 4; ++r)
      cmax[r] = fmaxf(fmaxf(pacc[0][r], pacc[1][r]), fmaxf(pacc[2][r], pacc[3][r]));
#pragma unroll
    for (int r = 0; r < 4; ++r) {
      cmax[r] = fmaxf(cmax[r], __shfl_xor(cmax[r], 1));
      cmax[r] = fmaxf(cmax[r], __shfl_xor(cmax[r], 2));
      cmax[r] = fmaxf(cmax[r], __shfl_xor(cmax[r], 4));
      cmax[r] = fmaxf(cmax[r], __shfl_xor(cmax[r], 8));
    }
    float alpha[4];
#pragma unroll
    for (int r = 0; r < 4; ++r) {
      const float mn = fmaxf(mrun[r], cmax[r]);
      alpha[r] = exp2f(mrun[r] - mn);
      mrun[r] = mn;
    }
#pragma unroll
    for (int ct = 0; ct < 4; ++ct)
#pragma unroll
      for (int r = 0; r < 4; ++r)
        pacc[ct][r] = exp2f(pacc[ct][r] - mrun[r]);
#pragma unroll
    for (int t = 0; t < 4; ++t)
#pragma unroll
      for (int r = 0; r < 4; ++r) oacc[t][r] *= alpha[r];
#pragma unroll
    for (int r = 0; r < 4; ++r) oacc2[r] *= alpha[r];

    // P -> LDS -> A-fragments; PV (+ denominator via ones row)
#pragma unroll
    for (int ct = 0; ct < 4; ++ct)
#pragma unroll
      for (int r = 0; r < 4; ++r)
        Pl[wave][fq * 4 + r][ct * 16 + fr] = f2bf(pacc[ct][r]);
    asm volatile("s_waitcnt lgkmcnt(0)" ::: "memory");
    __builtin_amdgcn_sched_barrier(0);
    const s16x8 ap0 = *(const s16x8*)&Pl[wave][fr][fq * 8];
    const s16x8 ap1 = *(const s16x8*)&Pl[wave][fr][32 + fq * 8];
    __builtin_amdgcn_s_setprio(1);
#pragma unroll
    for (int t = 0; t < 4; ++t) {
      oacc[t] = mfma16(ap0, *(const s16x8*)&Vs[t * 16 + fr][fq * 8], oacc[t]);
      oacc[t] = mfma16(ap1, *(const s16x8*)&Vs[t * 16 + fr][32 + fq * 8], oacc[t]);
    }
    oacc2 = mfma16(ap0, *(const s16x8*)&Vs[64 + fr][fq * 8], oacc2);
    oacc2 = mfma16(ap1, *(const s16x8*)&Vs[64 + fr][32 + fq * 8], oacc2);
    __builtin_amdgcn_s_setprio(0);
  }

  float linv[4];
#pragma unroll
  for (int r = 0; r < 4; ++r) {
    const float l = __shfl(oacc2[r], lane & 48);  // denominator from fr==0 lane
    linv[r] = 1.0f / l;
  }
#pragma unroll
  for (int t = 0; t < 4; ++t)
#pragma unroll
    for (int r = 0; r < 4; ++r) {
      const int gi = r0 + fq * 4 + r;
      CONCAT[((size_t)b * Ss + gi) * Dd + h * DKk + t * 16 + fr] =
          f2bf(oacc[t][r] * linv[r]);
    }
}

// ---------------------------------------------------------------------------
extern "C" void kernel_launch(void* const* d_in, const int* in_sizes, int n_in,
                              void* d_out, int out_size, void* d_ws,
                              size_t ws_size, hipStream_t stream) {
  (void)in_sizes; (void)n_in; (void)out_size; (void)ws_size;
  const float* q  = (const float*)d_in[0];
  const float* k  = (const float*)d_in[1];
  const float* v  = (const float*)d_in[2];
  // d_in[3] = mask: analytic (j <= i + MEM), unused
  const float* u  = (const float*)d_in[4];
  const float* vb = (const float*)d_in[5];
  const float* Wq = (const float*)d_in[6];
  const float* Wk = (const float*)d_in[7];
  const float* Wv = (const float*)d_in[8];
  const float* Wr = (const float*)d_in[9];
  const float* Wo = (const float*)d_in[10];
  const float* R  = (const float*)d_in[11];

  char* ws = (char*)d_ws;
  u16* QU = (u16*)ws; ws += 8388608;   // [B,H,S,DK] bf16
  u16* QV = (u16*)ws; ws += 8388608;
  u16* KH = (u16*)ws; ws += 16777216;  // [B,H,T,DK]
  u16* VT = (u16*)ws; ws += 16777216;  // [B,H,DK,T]
  u16* RH = (u16*)ws; ws += 4194304;   // [H,T,DK]
  u16* Wb = (u16*)ws;                  // 5 x 1M bf16 weights (10 MB)
  u16* CONCAT = Wb;                    // aliases WQ..WR (dead after gemm_qkvr)
  u16* WOb = Wb + ((size_t)4 << 20);

  cvt5<<<dim3(512, 5), 256, 0, stream>>>(Wq, Wk, Wv, Wr, Wo, Wb);
  gemm_qkvr<<<1408, 256, 0, stream>>>(q, k, v, R, Wb, QU, QV, KH, VT, RH, u, vb);
  attn2<<<512, 512, 0, stream>>>(QU, QV, KH, VT, RH, CONCAT);
  gemm_o<<<dim3(32, 8), 256, 0, stream>>>(CONCAT, WOb, (float*)d_out);
}